// Round 1
// baseline (2168.514 us; speedup 1.0000x reference)
//
#include <hip/hip_runtime.h>
#include <math.h>

#define PADID 400000
#define DD 256
#define DMM 512
#define LNEPS 1e-3f

__device__ __forceinline__ float sigmoidf_(float x){ return 1.0f/(1.0f+expf(-x)); }

// ---------------------------------------------------------------------------
// Fused neighbor encoder: grid = 2048 (q_l) + 2048 (q_r) + 5 (s_l) + 5 (s_r)
// Per block n: proj[k][d] = lrelu(sum_c cat[k][c]*W[d][c] + wb[d]+bb[d]),
// agg[d] = sum_k proj / max(deg,1); out = tanh(emb[id] + gate*agg)
// ---------------------------------------------------------------------------
__global__ __launch_bounds__(256) void ne_fused(
    const float* __restrict__ emb, const float* __restrict__ W,
    const float* __restrict__ wb, const float* __restrict__ bb,
    const float* __restrict__ gate_w, const float* __restrict__ gate_temp,
    const int* __restrict__ q_l1, const int* __restrict__ q_deg_l,
    const int* __restrict__ q_r1, const int* __restrict__ q_deg_r,
    const int* __restrict__ s_l1, const int* __restrict__ s_deg_l,
    const int* __restrict__ s_r1, const int* __restrict__ s_deg_r,
    const int* __restrict__ query, const int* __restrict__ support,
    float* __restrict__ q_vec, float* __restrict__ s_vec)
{
    __shared__ int   rel_s[64];
    __shared__ int   ent_s[64];
    __shared__ float cat_lds[32][64];    // [c][k]
    __shared__ float W_lds[32][256];     // [c][d]
    __shared__ float red[8][256];        // [kt][d]
    __shared__ float gw_s[64];
    __shared__ float gate_sh;

    int bid = blockIdx.x;
    const int* conn; const int* deg; const int* ids; float* out;
    int n, col, ids_off;
    if (bid < 2048)      { n = bid;      conn = q_l1; deg = q_deg_l; ids = query;   ids_off = 0; out = q_vec; col = 0;   }
    else if (bid < 4096) { n = bid-2048; conn = q_r1; deg = q_deg_r; ids = query;   ids_off = 1; out = q_vec; col = 256; }
    else if (bid < 4101) { n = bid-4096; conn = s_l1; deg = s_deg_l; ids = support; ids_off = 0; out = s_vec; col = 0;   }
    else                 { n = bid-4101; conn = s_r1; deg = s_deg_r; ids = support; ids_off = 1; out = s_vec; col = 256; }

    int t = threadIdx.x;

    if (t < 128) {
        int v = conn[n*128 + t];
        if (t & 1) ent_s[t>>1] = v; else rel_s[t>>1] = v;
    }
    __syncthreads();
    if (t < 64) {
        int r = rel_s[t];
        int nr = (r == PADID) ? 0 : r;
        gw_s[t] = gate_w[nr];
    }
    __syncthreads();
    if (t == 0) {
        float s = 0.0f;
        for (int k = 0; k < 64; k++) s += gw_s[k];
        float g = sigmoidf_((s * (1.0f/64.0f)) / gate_temp[0]);
        if (!((float)deg[n] > 0.0f)) g = 1.0f;
        gate_sh = g;
    }

    const int kt = t >> 5;              // 0..7
    const int dt = t & 31;              // 0..31
    const int k0 = kt * 8;
    const int dA = dt * 4;              // first 4 d's
    const int dB = 128 + dt * 4;        // second 4 d's

    float acc[8][8];
    #pragma unroll
    for (int i = 0; i < 8; i++)
        #pragma unroll
        for (int j = 0; j < 8; j++) acc[i][j] = 0.0f;

    for (int chunk = 0; chunk < 16; chunk++) {
        const int c0 = chunk * 32;
        const int side = (c0 >= 256);
        const int cg0 = side ? (c0 - 256) : c0;
        // stage cat[c][k] for 32 c's
        {
            int k = t >> 2, part = t & 3;
            int row = side ? ent_s[k] : rel_s[k];
            const float* src = emb + (long long)row * DD + cg0 + part * 8;
            float4 v0 = *(const float4*)src;
            float4 v1 = *(const float4*)(src + 4);
            int cb = part * 8;
            cat_lds[cb+0][k] = v0.x; cat_lds[cb+1][k] = v0.y;
            cat_lds[cb+2][k] = v0.z; cat_lds[cb+3][k] = v0.w;
            cat_lds[cb+4][k] = v1.x; cat_lds[cb+5][k] = v1.y;
            cat_lds[cb+6][k] = v1.z; cat_lds[cb+7][k] = v1.w;
        }
        // stage W[c][d], d = t
        {
            const float* wsrc = W + (long long)t * 512 + c0;
            #pragma unroll
            for (int q = 0; q < 8; q++) {
                float4 v = *(const float4*)(wsrc + q*4);
                W_lds[q*4+0][t] = v.x; W_lds[q*4+1][t] = v.y;
                W_lds[q*4+2][t] = v.z; W_lds[q*4+3][t] = v.w;
            }
        }
        __syncthreads();
        #pragma unroll 4
        for (int c = 0; c < 32; c++) {
            const float4 a0 = *(const float4*)&cat_lds[c][k0];
            const float4 a1 = *(const float4*)&cat_lds[c][k0+4];
            const float4 b0 = *(const float4*)&W_lds[c][dA];
            const float4 b1 = *(const float4*)&W_lds[c][dB];
            const float av[8] = {a0.x,a0.y,a0.z,a0.w,a1.x,a1.y,a1.z,a1.w};
            const float bv[8] = {b0.x,b0.y,b0.z,b0.w,b1.x,b1.y,b1.z,b1.w};
            #pragma unroll
            for (int ki = 0; ki < 8; ki++)
                #pragma unroll
                for (int dj = 0; dj < 8; dj++)
                    acc[ki][dj] = fmaf(av[ki], bv[dj], acc[ki][dj]);
        }
        __syncthreads();
    }

    // epilogue: leaky_relu + PAD mask + sum over k
    float bias_j[8];
    #pragma unroll
    for (int j = 0; j < 4; j++) {
        bias_j[j]   = wb[dA+j] + bb[dA+j];
        bias_j[4+j] = wb[dB+j] + bb[dB+j];
    }
    float p[8];
    #pragma unroll
    for (int j = 0; j < 8; j++) p[j] = 0.0f;
    #pragma unroll
    for (int ki = 0; ki < 8; ki++) {
        int r = rel_s[k0+ki];
        if (r != PADID) {
            #pragma unroll
            for (int dj = 0; dj < 8; dj++) {
                float v = acc[ki][dj] + bias_j[dj];
                v = (v > 0.0f) ? v : 0.01f * v;
                p[dj] += v;
            }
        }
    }
    #pragma unroll
    for (int j = 0; j < 4; j++) {
        red[kt][dA+j] = p[j];
        red[kt][dB+j] = p[4+j];
    }
    __syncthreads();

    // t indexes d now
    float agg = 0.0f;
    #pragma unroll
    for (int g = 0; g < 8; g++) agg += red[g][t];
    float degf = fmaxf((float)deg[n], 1.0f);
    agg /= degf;
    int id = ids[n*2 + ids_off];
    float o = tanhf(emb[(long long)id * DD + t] + gate_sh * agg);
    out[(long long)n * DMM + col + t] = o;
}

// ---------------------------------------------------------------------------
// Generic fp32 GEMM: C[n][m] = act( sum_k A[n][k]*Wt[m][k] + bias[m] + add[n][m] )
// Tiles 128x128, 256 threads, 8x8 micro-tile. ACT: 0 none, 1 relu.
// ---------------------------------------------------------------------------
template<int ACT, bool HAS_ADD>
__global__ __launch_bounds__(256) void gemm_kernel(
    const float* __restrict__ A, const float* __restrict__ Wt,
    const float* __restrict__ bias, const float* __restrict__ add,
    float* __restrict__ C, int N, int M, int K, int ldw)
{
    __shared__ float A_lds[16][128];
    __shared__ float W_lds[16][128];
    const int t = threadIdx.x;
    const int bm0 = blockIdx.x * 128;
    const int bn0 = blockIdx.y * 128;
    const int nt = t >> 4, mt = t & 15;
    const int n0 = nt * 8;
    const int mA = mt * 4, mB = 64 + mt * 4;
    const int rowL = t >> 1, half = t & 1;

    float acc[8][8];
    #pragma unroll
    for (int i = 0; i < 8; i++)
        #pragma unroll
        for (int j = 0; j < 8; j++) acc[i][j] = 0.0f;

    for (int c0 = 0; c0 < K; c0 += 16) {
        {
            int grow = bn0 + rowL;
            float4 v0 = make_float4(0,0,0,0), v1 = make_float4(0,0,0,0);
            if (grow < N) {
                const float* pA = A + (long long)grow * K + c0 + half * 8;
                v0 = *(const float4*)pA; v1 = *(const float4*)(pA + 4);
            }
            int cb = half * 8;
            A_lds[cb+0][rowL] = v0.x; A_lds[cb+1][rowL] = v0.y;
            A_lds[cb+2][rowL] = v0.z; A_lds[cb+3][rowL] = v0.w;
            A_lds[cb+4][rowL] = v1.x; A_lds[cb+5][rowL] = v1.y;
            A_lds[cb+6][rowL] = v1.z; A_lds[cb+7][rowL] = v1.w;
        }
        {
            const float* pW = Wt + (long long)(bm0 + rowL) * ldw + c0 + half * 8;
            float4 v0 = *(const float4*)pW, v1 = *(const float4*)(pW + 4);
            int cb = half * 8;
            W_lds[cb+0][rowL] = v0.x; W_lds[cb+1][rowL] = v0.y;
            W_lds[cb+2][rowL] = v0.z; W_lds[cb+3][rowL] = v0.w;
            W_lds[cb+4][rowL] = v1.x; W_lds[cb+5][rowL] = v1.y;
            W_lds[cb+6][rowL] = v1.z; W_lds[cb+7][rowL] = v1.w;
        }
        __syncthreads();
        #pragma unroll 4
        for (int c = 0; c < 16; c++) {
            const float4 a0 = *(const float4*)&A_lds[c][n0];
            const float4 a1 = *(const float4*)&A_lds[c][n0+4];
            const float4 b0 = *(const float4*)&W_lds[c][mA];
            const float4 b1 = *(const float4*)&W_lds[c][mB];
            const float av[8] = {a0.x,a0.y,a0.z,a0.w,a1.x,a1.y,a1.z,a1.w};
            const float bv[8] = {b0.x,b0.y,b0.z,b0.w,b1.x,b1.y,b1.z,b1.w};
            #pragma unroll
            for (int i = 0; i < 8; i++)
                #pragma unroll
                for (int j = 0; j < 8; j++)
                    acc[i][j] = fmaf(av[i], bv[j], acc[i][j]);
        }
        __syncthreads();
    }

    #pragma unroll
    for (int i = 0; i < 8; i++) {
        int nrow = bn0 + n0 + i;
        if (nrow < N) {
            long long base = (long long)nrow * M + bm0;
            float4 o0, o1;
            float* r0 = (float*)&o0; float* r1 = (float*)&o1;
            #pragma unroll
            for (int q = 0; q < 4; q++) {
                float vA = acc[i][q]   + bias[bm0 + mA + q];
                float vB = acc[i][4+q] + bias[bm0 + mB + q];
                if (HAS_ADD) { vA += add[base + mA + q]; vB += add[base + mB + q]; }
                if (ACT == 1) { vA = fmaxf(vA, 0.0f); vB = fmaxf(vB, 0.0f); }
                r0[q] = vA; r1[q] = vB;
            }
            *(float4*)&C[base + mA] = o0;
            *(float4*)&C[base + mB] = o1;
        }
    }
}

// ---------------------------------------------------------------------------
// LayerNorm with ddof=1: out = (z-mu)/(std+eps)*a + b, row length 512
// ---------------------------------------------------------------------------
__global__ __launch_bounds__(256) void ln_kernel(
    const float* __restrict__ z, const float* __restrict__ a,
    const float* __restrict__ b, float* __restrict__ o)
{
    __shared__ float red[256];
    int n = blockIdx.x, t = threadIdx.x;
    const float* zp = z + (long long)n * DMM;
    float2 v = *(const float2*)(zp + t*2);
    red[t] = v.x + v.y;
    __syncthreads();
    for (int off = 128; off > 0; off >>= 1) {
        if (t < off) red[t] += red[t+off];
        __syncthreads();
    }
    float mu = red[0] * (1.0f/512.0f);
    __syncthreads();
    float d0 = v.x - mu, d1 = v.y - mu;
    red[t] = d0*d0 + d1*d1;
    __syncthreads();
    for (int off = 128; off > 0; off >>= 1) {
        if (t < off) red[t] += red[t+off];
        __syncthreads();
    }
    float var = red[0] * (1.0f/511.0f);
    float inv = 1.0f / (sqrtf(var) + LNEPS);
    float* op = o + (long long)n * DMM;
    op[t*2]   = d0 * inv * a[t*2]   + b[t*2];
    op[t*2+1] = d1 * inv * a[t*2+1] + b[t*2+1];
}

__global__ __launch_bounds__(256) void mean5_kernel(
    const float* __restrict__ se, float* __restrict__ sg)
{
    int d = blockIdx.x * 256 + threadIdx.x;
    if (d < 512) {
        float s = 0.0f;
        #pragma unroll
        for (int f = 0; f < 5; f++) s += se[f*512 + d];
        sg[d] = s * 0.2f;
    }
}

__global__ __launch_bounds__(256) void vecadd_kernel(
    const float* __restrict__ x, const float* __restrict__ y,
    float* __restrict__ o, int n)
{
    int i = blockIdx.x * 256 + threadIdx.x;
    if (i < n) o[i] = x[i] + y[i];
}

// svec_g[m] = sum_k s_g[k] * W_hh[m][512+k]
__global__ __launch_bounds__(256) void svecg_kernel(
    const float* __restrict__ sg, const float* __restrict__ Whh,
    float* __restrict__ outv)
{
    __shared__ float sgl[512];
    int t = threadIdx.x;
    sgl[t] = sg[t]; sgl[256+t] = sg[256+t];
    __syncthreads();
    int m = blockIdx.x * 256 + t;
    const float* wp = Whh + (long long)m * 1024 + 512;
    float s = 0.0f;
    for (int k = 0; k < 512; k += 4) {
        float4 w = *(const float4*)(wp + k);
        s += sgl[k]*w.x + sgl[k+1]*w.y + sgl[k+2]*w.z + sgl[k+3]*w.w;
    }
    outv[m] = s;
}

// LSTM elementwise: gates (2048x4096) -> c (2048x1024), h (2048x512)
template<bool FIRST>
__global__ __launch_bounds__(256) void lstm_ew_kernel(
    const float* __restrict__ gates, float* __restrict__ c,
    const float* __restrict__ qenc, float* __restrict__ h)
{
    int idx = blockIdx.x * 256 + threadIdx.x;     // n*1024 + j
    int n = idx >> 10, j = idx & 1023;
    const float* g = gates + (long long)n * 4096;
    float ig = g[j], fg = g[1024+j], gg = g[2048+j], og = g[3072+j];
    float cv = FIRST ? 0.0f : c[idx];
    float si = sigmoidf_(ig), sf = sigmoidf_(fg), so = sigmoidf_(og);
    cv = sf * cv + si * tanhf(gg);
    c[idx] = cv;
    float hn = so * tanhf(cv);
    if (j < 512) h[(long long)n * 512 + j] = qenc[(long long)n * 512 + j] + hn;
}

// out[n] = dot(h[n], s_g), one wave per n
__global__ __launch_bounds__(256) void dot_kernel(
    const float* __restrict__ h, const float* __restrict__ sg,
    float* __restrict__ out)
{
    int w = threadIdx.x >> 6, lane = threadIdx.x & 63;
    int n = blockIdx.x * 4 + w;
    const float* hp = h + (long long)n * 512 + lane * 8;
    const float* sp = sg + lane * 8;
    float4 a0 = *(const float4*)hp, a1 = *(const float4*)(hp+4);
    float4 b0 = *(const float4*)sp, b1 = *(const float4*)(sp+4);
    float p = a0.x*b0.x + a0.y*b0.y + a0.z*b0.z + a0.w*b0.w
            + a1.x*b1.x + a1.y*b1.y + a1.z*b1.z + a1.w*b1.w;
    #pragma unroll
    for (int off = 32; off > 0; off >>= 1) p += __shfl_down(p, off);
    if (lane == 0) out[n] = p;
}

extern "C" void kernel_launch(void* const* d_in, const int* in_sizes, int n_in,
                              void* d_out, int out_size, void* d_ws, size_t ws_size,
                              hipStream_t stream)
{
    (void)in_sizes; (void)n_in; (void)out_size; (void)ws_size;
    const float* emb       = (const float*)d_in[0];
    const float* gcn_W     = (const float*)d_in[1];
    const float* gcn_wb    = (const float*)d_in[2];
    const float* gcn_b     = (const float*)d_in[3];
    const float* gate_w    = (const float*)d_in[4];
    const float* gate_temp = (const float*)d_in[5];
    const float* p1_W      = (const float*)d_in[6];
    const float* p1_b      = (const float*)d_in[7];
    const float* p2_W      = (const float*)d_in[8];
    const float* p2_b      = (const float*)d_in[9];
    const float* ln_a      = (const float*)d_in[10];
    const float* ln_b      = (const float*)d_in[11];
    const float* W_ih      = (const float*)d_in[12];
    const float* W_hh      = (const float*)d_in[13];
    const float* b_ih      = (const float*)d_in[14];
    const float* b_hh      = (const float*)d_in[15];
    const int*   query     = (const int*)d_in[16];
    const int*   support   = (const int*)d_in[17];
    const int*   q_l1      = (const int*)d_in[18];
    const int*   q_deg_l   = (const int*)d_in[19];
    const int*   q_r1      = (const int*)d_in[20];
    const int*   q_deg_r   = (const int*)d_in[21];
    const int*   s_l1      = (const int*)d_in[22];
    const int*   s_deg_l   = (const int*)d_in[23];
    const int*   s_r1      = (const int*)d_in[24];
    const int*   s_deg_r   = (const int*)d_in[25];
    float* out = (float*)d_out;

    float* ws = (float*)d_ws;
    size_t off = 0;
    auto alloc = [&](size_t nf) { float* p = ws + off; off += (nf + 63) & ~(size_t)63; return p; };
    float* q_vec  = alloc(2048*512);
    float* s_vec  = alloc(5*512);
    float* q_enc  = alloc(2048*512);
    float* s_enc  = alloc(5*512);
    float* s_g    = alloc(512);
    float* bias0  = alloc(4096);
    float* svec_g = alloc(4096);
    float* c_st   = alloc(2048*1024);
    float* h      = alloc(2048*512);
    float* G0     = alloc((size_t)2048*4096);
    float* gates  = alloc((size_t)2048*4096);
    // aliases inside gates region (dead before gates is first written)
    float* h1_q = gates;
    float* z_q  = gates + 2048*1024;
    float* h1_s = z_q + 2048*512;
    float* z_s  = h1_s + 5*1024;

    // 1) neighbor encoders (fused 4-way)
    ne_fused<<<4106, 256, 0, stream>>>(emb, gcn_W, gcn_wb, gcn_b, gate_w, gate_temp,
        q_l1, q_deg_l, q_r1, q_deg_r, s_l1, s_deg_l, s_r1, s_deg_r,
        query, support, q_vec, s_vec);

    // 2) support encoder on queries
    gemm_kernel<1,false><<<dim3(8,16), 256, 0, stream>>>(q_vec, p1_W, p1_b, nullptr, h1_q, 2048, 1024, 512, 512);
    gemm_kernel<0,true ><<<dim3(4,16), 256, 0, stream>>>(h1_q, p2_W, p2_b, q_vec, z_q, 2048, 512, 1024, 1024);
    ln_kernel<<<2048, 256, 0, stream>>>(z_q, ln_a, ln_b, q_enc);

    // 3) support encoder on supports + mean -> s_g
    gemm_kernel<1,false><<<dim3(8,1), 256, 0, stream>>>(s_vec, p1_W, p1_b, nullptr, h1_s, 5, 1024, 512, 512);
    gemm_kernel<0,true ><<<dim3(4,1), 256, 0, stream>>>(h1_s, p2_W, p2_b, s_vec, z_s, 5, 512, 1024, 1024);
    ln_kernel<<<5, 256, 0, stream>>>(z_s, ln_a, ln_b, s_enc);
    mean5_kernel<<<2, 256, 0, stream>>>(s_enc, s_g);

    // 4) LSTM preludes
    vecadd_kernel<<<16, 256, 0, stream>>>(b_ih, b_hh, bias0, 4096);
    svecg_kernel<<<16, 256, 0, stream>>>(s_g, W_hh, svec_g);
    gemm_kernel<0,false><<<dim3(32,16), 256, 0, stream>>>(q_enc, W_ih, bias0, nullptr, G0, 2048, 4096, 512, 512);

    // 5) LSTM steps (step 1: h_r = 0 -> gates = G0)
    lstm_ew_kernel<true><<<8192, 256, 0, stream>>>(G0, c_st, q_enc, h);
    for (int s2 = 0; s2 < 3; s2++) {
        gemm_kernel<0,true><<<dim3(32,16), 256, 0, stream>>>(h, W_hh, svec_g, G0, gates, 2048, 4096, 512, 1024);
        lstm_ew_kernel<false><<<8192, 256, 0, stream>>>(gates, c_st, q_enc, h);
    }

    // 6) final scores
    dot_kernel<<<512, 256, 0, stream>>>(h, s_g, out);
}

// Round 2
// 886.050 us; speedup vs baseline: 2.4474x; 2.4474x over previous
//
#include <hip/hip_runtime.h>
#include <math.h>

#define PADID 400000

typedef __attribute__((ext_vector_type(8))) short bf16x8;
typedef __attribute__((ext_vector_type(4))) float f32x4;

__device__ __forceinline__ float sigmoidf_(float x){ return 1.0f/(1.0f+expf(-x)); }

__device__ __forceinline__ unsigned short f2bf(float f){
    unsigned u = __float_as_uint(f);
    u += 0x7FFFu + ((u >> 16) & 1u);
    return (unsigned short)(u >> 16);
}
__device__ __forceinline__ float bf2f(unsigned short s){
    return __uint_as_float(((unsigned)s) << 16);
}

// ---------------------------------------------------------------------------
// Weight preconversion fp32 -> bf16 (one pass over all weight matrices).
// seg4 = W_hh[:, :512] slice (row stride 1024).
// ---------------------------------------------------------------------------
__global__ __launch_bounds__(256) void preconvert(
    const float* __restrict__ gcnW, const float* __restrict__ p1W,
    const float* __restrict__ p2W, const float* __restrict__ Wih,
    const float* __restrict__ Whh,
    unsigned short* __restrict__ wgcn, unsigned short* __restrict__ p1w,
    unsigned short* __restrict__ p2w, unsigned short* __restrict__ wih,
    unsigned short* __restrict__ whh)
{
    long long i = ((long long)blockIdx.x * 256 + threadIdx.x) * 4;
    const float* src; unsigned short* dst; long long off;
    float4 v;
    if (i < 131072LL)        { src = gcnW; dst = wgcn; off = i; }
    else if (i < 655360LL)   { src = p1W;  dst = p1w;  off = i - 131072LL; }
    else if (i < 1179648LL)  { src = p2W;  dst = p2w;  off = i - 655360LL; }
    else if (i < 3276800LL)  { src = Wih;  dst = wih;  off = i - 1179648LL; }
    else if (i < 5373952LL)  {
        off = i - 3276800LL;
        long long row = off >> 9, col = off & 511;
        v = *(const float4*)(Whh + row * 1024 + col);
        unsigned p0 = f2bf(v.x) | ((unsigned)f2bf(v.y) << 16);
        unsigned p1 = f2bf(v.z) | ((unsigned)f2bf(v.w) << 16);
        *(uint2*)(whh + off) = make_uint2(p0, p1);
        return;
    } else return;
    v = *(const float4*)(src + off);
    unsigned p0 = f2bf(v.x) | ((unsigned)f2bf(v.y) << 16);
    unsigned p1 = f2bf(v.z) | ((unsigned)f2bf(v.w) << 16);
    *(uint2*)(dst + off) = make_uint2(p0, p1);
}

// ---------------------------------------------------------------------------
// Neighbor encoder, MFMA version. One block per sample.
// A = gathered emb rows (64 x 512, fp32->bf16 in staging), B = gcn_W bf16
// (256 d-rows x 512 c-cols). Epilogue: bias+leakyrelu+PAD-mask+sum/deg,
// gate, tanh(emb[self]+gate*agg) -> bf16 output.
// ---------------------------------------------------------------------------
__global__ __launch_bounds__(256) void ne_fused(
    const float* __restrict__ emb, const unsigned short* __restrict__ Wbf,
    const float* __restrict__ wb, const float* __restrict__ bb,
    const float* __restrict__ gate_w, const float* __restrict__ gate_temp,
    const int* __restrict__ q_l1, const int* __restrict__ q_deg_l,
    const int* __restrict__ q_r1, const int* __restrict__ q_deg_r,
    const int* __restrict__ s_l1, const int* __restrict__ s_deg_l,
    const int* __restrict__ s_r1, const int* __restrict__ s_deg_r,
    const int* __restrict__ query, const int* __restrict__ support,
    unsigned short* __restrict__ q_vec_bf, unsigned short* __restrict__ s_vec_bf)
{
    __shared__ int   rel_s[64];
    __shared__ int   ent_s[64];
    __shared__ unsigned short A_lds[64 * 72];
    __shared__ unsigned short B_lds[256 * 72];
    __shared__ float red[4][4][64];
    __shared__ float gw_s[64];
    __shared__ float gate_sh;

    int bid = blockIdx.x;
    const int* conn; const int* deg; const int* ids; unsigned short* out;
    int n, col, ids_off;
    if (bid < 2048)      { n = bid;      conn = q_l1; deg = q_deg_l; ids = query;   ids_off = 0; out = q_vec_bf; col = 0;   }
    else if (bid < 4096) { n = bid-2048; conn = q_r1; deg = q_deg_r; ids = query;   ids_off = 1; out = q_vec_bf; col = 256; }
    else if (bid < 4101) { n = bid-4096; conn = s_l1; deg = s_deg_l; ids = support; ids_off = 0; out = s_vec_bf; col = 0;   }
    else                 { n = bid-4101; conn = s_r1; deg = s_deg_r; ids = support; ids_off = 1; out = s_vec_bf; col = 256; }

    const int t = threadIdx.x;
    const int lane = t & 63, w = t >> 6, lr = lane & 15, kg = lane >> 4;

    if (t < 128) {
        int v = conn[n*128 + t];
        if (t & 1) ent_s[t>>1] = v; else rel_s[t>>1] = v;
    }
    __syncthreads();
    if (t < 64) {
        int r = rel_s[t];
        gw_s[t] = gate_w[(r == PADID) ? 0 : r];
    }
    __syncthreads();
    if (t == 0) {
        float s = 0.0f;
        for (int k = 0; k < 64; k++) s += gw_s[k];
        float g = sigmoidf_((s * (1.0f/64.0f)) / gate_temp[0]);
        if (!((float)deg[n] > 0.0f)) g = 1.0f;
        gate_sh = g;
    }

    f32x4 acc[4][4];
    #pragma unroll
    for (int i = 0; i < 4; i++)
        #pragma unroll
        for (int j = 0; j < 4; j++)
            acc[i][j] = (f32x4){0.f,0.f,0.f,0.f};

    for (int ch = 0; ch < 8; ch++) {
        const int c0 = ch * 64;
        const int side = (ch >= 4);
        const int cg0 = (ch & 3) * 64;
        // A stage: 64 rows x 64 cols, fp32 gather -> bf16
        {
            int r = t >> 2, seg = t & 3;
            int rowid = side ? ent_s[r] : rel_s[r];
            const float* src = emb + (long long)rowid * 256 + cg0 + seg * 16;
            float4 v0 = *(const float4*)(src);
            float4 v1 = *(const float4*)(src + 4);
            float4 v2 = *(const float4*)(src + 8);
            float4 v3 = *(const float4*)(src + 12);
            bf16x8 o0, o1;
            o0[0]=(short)f2bf(v0.x); o0[1]=(short)f2bf(v0.y); o0[2]=(short)f2bf(v0.z); o0[3]=(short)f2bf(v0.w);
            o0[4]=(short)f2bf(v1.x); o0[5]=(short)f2bf(v1.y); o0[6]=(short)f2bf(v1.z); o0[7]=(short)f2bf(v1.w);
            o1[0]=(short)f2bf(v2.x); o1[1]=(short)f2bf(v2.y); o1[2]=(short)f2bf(v2.z); o1[3]=(short)f2bf(v2.w);
            o1[4]=(short)f2bf(v3.x); o1[5]=(short)f2bf(v3.y); o1[6]=(short)f2bf(v3.z); o1[7]=(short)f2bf(v3.w);
            *(bf16x8*)&A_lds[r*72 + seg*16]     = o0;
            *(bf16x8*)&A_lds[r*72 + seg*16 + 8] = o1;
        }
        // B stage: 256 rows x 64 cols bf16 copy
        #pragma unroll
        for (int j = 0; j < 8; j++) {
            int row = j * 32 + (t >> 3);
            const unsigned short* src = Wbf + (long long)row * 512 + c0 + (t & 7) * 8;
            bf16x8 v = *(const bf16x8*)src;
            *(bf16x8*)&B_lds[row*72 + (t & 7) * 8] = v;
        }
        __syncthreads();
        #pragma unroll
        for (int ks = 0; ks < 64; ks += 32) {
            bf16x8 a[4], b[4];
            #pragma unroll
            for (int rt = 0; rt < 4; rt++)
                a[rt] = *(const bf16x8*)&A_lds[(rt*16 + lr)*72 + ks + kg*8];
            #pragma unroll
            for (int ct = 0; ct < 4; ct++)
                b[ct] = *(const bf16x8*)&B_lds[(w*64 + ct*16 + lr)*72 + ks + kg*8];
            #pragma unroll
            for (int rt = 0; rt < 4; rt++)
                #pragma unroll
                for (int ct = 0; ct < 4; ct++)
                    acc[rt][ct] = __builtin_amdgcn_mfma_f32_16x16x32_bf16(a[rt], b[ct], acc[rt][ct], 0, 0, 0);
        }
        __syncthreads();
    }

    // epilogue: bias + leaky_relu + PAD mask + sum over 64 neighbor rows
    #pragma unroll
    for (int ct = 0; ct < 4; ct++) {
        int d = w*64 + ct*16 + lr;
        float bd = wb[d] + bb[d];
        float pp = 0.0f;
        #pragma unroll
        for (int rt = 0; rt < 4; rt++) {
            int rbase = rt*16 + kg*4;
            #pragma unroll
            for (int reg = 0; reg < 4; reg++) {
                if (rel_s[rbase + reg] != PADID) {
                    float v = acc[rt][ct][reg] + bd;
                    v = (v > 0.0f) ? v : 0.01f * v;
                    pp += v;
                }
            }
        }
        red[w][kg][ct*16 + lr] = pp;
    }
    __syncthreads();

    int w2 = t >> 6, cw = t & 63;
    float agg = red[w2][0][cw] + red[w2][1][cw] + red[w2][2][cw] + red[w2][3][cw];
    float degf = fmaxf((float)deg[n], 1.0f);
    agg /= degf;
    int id = ids[n*2 + ids_off];
    float o = tanhf(emb[(long long)id * 256 + t] + gate_sh * agg);
    out[(long long)n * 512 + col + t] = f2bf(o);
}

// ---------------------------------------------------------------------------
// Generic bf16 MFMA GEMM: C[n][m] = act( A[n][:] . B[m][:] + bias[m] + bias2[m]
//                                        + add[n][m] )
// Block tile 128x128 (4 waves of 64x64), BK=64, LDS stride 72 (pad).
// ---------------------------------------------------------------------------
template<int HB, int HB2, int HADD, int ADDBF, int RELU, int WF, int WB>
__global__ __launch_bounds__(256) void mfma_gemm(
    const unsigned short* __restrict__ A, const unsigned short* __restrict__ B,
    const float* __restrict__ bias, const float* __restrict__ bias2,
    const void* __restrict__ add, float* __restrict__ Cf,
    unsigned short* __restrict__ Cb, int N, int M, int K)
{
    __shared__ unsigned short A_lds[128 * 72];
    __shared__ unsigned short B_lds[128 * 72];
    const int t = threadIdx.x;
    const int bm0 = blockIdx.x * 128, bn0 = blockIdx.y * 128;
    const int lane = t & 63, w = t >> 6, wn = w >> 1, wm = w & 1;
    const int lr = lane & 15, kg = lane >> 4;

    f32x4 acc[4][4];
    #pragma unroll
    for (int i = 0; i < 4; i++)
        #pragma unroll
        for (int j = 0; j < 4; j++)
            acc[i][j] = (f32x4){0.f,0.f,0.f,0.f};

    const int r = t >> 1, half = t & 1;
    const unsigned short* Ap = A + (size_t)(bn0 + r) * K + half * 32;
    const unsigned short* Bp = B + (size_t)(bm0 + r) * K + half * 32;
    unsigned short* Aw = &A_lds[r*72 + half*32];
    unsigned short* Bw = &B_lds[r*72 + half*32];

    for (int c0 = 0; c0 < K; c0 += 64) {
        #pragma unroll
        for (int q = 0; q < 4; q++) {
            bf16x8 va = *(const bf16x8*)(Ap + c0 + q*8);
            bf16x8 vb = *(const bf16x8*)(Bp + c0 + q*8);
            *(bf16x8*)(Aw + q*8) = va;
            *(bf16x8*)(Bw + q*8) = vb;
        }
        __syncthreads();
        #pragma unroll
        for (int ks = 0; ks < 64; ks += 32) {
            bf16x8 a[4], b[4];
            #pragma unroll
            for (int rt = 0; rt < 4; rt++)
                a[rt] = *(const bf16x8*)&A_lds[(wn*64 + rt*16 + lr)*72 + ks + kg*8];
            #pragma unroll
            for (int ct = 0; ct < 4; ct++)
                b[ct] = *(const bf16x8*)&B_lds[(wm*64 + ct*16 + lr)*72 + ks + kg*8];
            #pragma unroll
            for (int rt = 0; rt < 4; rt++)
                #pragma unroll
                for (int ct = 0; ct < 4; ct++)
                    acc[rt][ct] = __builtin_amdgcn_mfma_f32_16x16x32_bf16(a[rt], b[ct], acc[rt][ct], 0, 0, 0);
        }
        __syncthreads();
    }

    float bsum[4];
    #pragma unroll
    for (int ct = 0; ct < 4; ct++) {
        int m = bm0 + wm*64 + ct*16 + lr;
        float bv = 0.0f;
        if (HB)  bv += bias[m];
        if (HB2) bv += bias2[m];
        bsum[ct] = bv;
    }
    #pragma unroll
    for (int rt = 0; rt < 4; rt++) {
        #pragma unroll
        for (int reg = 0; reg < 4; reg++) {
            int n = bn0 + wn*64 + rt*16 + kg*4 + reg;
            if (n < N) {
                size_t rowb = (size_t)n * M + bm0 + wm*64;
                #pragma unroll
                for (int ct = 0; ct < 4; ct++) {
                    size_t idx = rowb + ct*16 + lr;
                    float v = acc[rt][ct][reg] + bsum[ct];
                    if (HADD) {
                        if (ADDBF) v += bf2f(((const unsigned short*)add)[idx]);
                        else       v += ((const float*)add)[idx];
                    }
                    if (RELU) v = fmaxf(v, 0.0f);
                    if (WF) Cf[idx] = v;
                    if (WB) Cb[idx] = f2bf(v);
                }
            }
        }
    }
}

// ---------------------------------------------------------------------------
// LayerNorm ddof=1, row length 512; optional bf16 copy output
// ---------------------------------------------------------------------------
__global__ __launch_bounds__(256) void ln_kernel(
    const float* __restrict__ z, const float* __restrict__ a,
    const float* __restrict__ b, float* __restrict__ o,
    unsigned short* __restrict__ ob)
{
    __shared__ float red[256];
    int n = blockIdx.x, t = threadIdx.x;
    const float* zp = z + (long long)n * 512;
    float2 v = *(const float2*)(zp + t*2);
    red[t] = v.x + v.y;
    __syncthreads();
    for (int off = 128; off > 0; off >>= 1) {
        if (t < off) red[t] += red[t+off];
        __syncthreads();
    }
    float mu = red[0] * (1.0f/512.0f);
    __syncthreads();
    float d0 = v.x - mu, d1 = v.y - mu;
    red[t] = d0*d0 + d1*d1;
    __syncthreads();
    for (int off = 128; off > 0; off >>= 1) {
        if (t < off) red[t] += red[t+off];
        __syncthreads();
    }
    float var = red[0] * (1.0f/511.0f);
    float inv = 1.0f / (sqrtf(var) + 1e-3f);
    float r0 = d0 * inv * a[t*2]   + b[t*2];
    float r1 = d1 * inv * a[t*2+1] + b[t*2+1];
    float* op = o + (long long)n * 512;
    op[t*2] = r0; op[t*2+1] = r1;
    if (ob) {
        unsigned short* obp = ob + (long long)n * 512;
        obp[t*2] = f2bf(r0); obp[t*2+1] = f2bf(r1);
    }
}

__global__ __launch_bounds__(256) void mean5_kernel(
    const float* __restrict__ se, float* __restrict__ sg)
{
    int d = blockIdx.x * 256 + threadIdx.x;
    if (d < 512) {
        float s = 0.0f;
        #pragma unroll
        for (int f = 0; f < 5; f++) s += se[f*512 + d];
        sg[d] = s * 0.2f;
    }
}

__global__ __launch_bounds__(256) void vecadd_kernel(
    const float* __restrict__ x, const float* __restrict__ y,
    float* __restrict__ o, int n)
{
    int i = blockIdx.x * 256 + threadIdx.x;
    if (i < n) o[i] = x[i] + y[i];
}

__global__ __launch_bounds__(256) void svecg_kernel(
    const float* __restrict__ sg, const float* __restrict__ Whh,
    float* __restrict__ outv)
{
    __shared__ float sgl[512];
    int t = threadIdx.x;
    sgl[t] = sg[t]; sgl[256+t] = sg[256+t];
    __syncthreads();
    int m = blockIdx.x * 256 + t;
    const float* wp = Whh + (long long)m * 1024 + 512;
    float s = 0.0f;
    for (int k = 0; k < 512; k += 4) {
        float4 wv = *(const float4*)(wp + k);
        s += sgl[k]*wv.x + sgl[k+1]*wv.y + sgl[k+2]*wv.z + sgl[k+3]*wv.w;
    }
    outv[m] = s;
}

template<bool FIRST, bool GBF>
__global__ __launch_bounds__(256) void lstm_ew_kernel(
    const void* __restrict__ gates, float* __restrict__ c,
    const float* __restrict__ qenc, float* __restrict__ h,
    unsigned short* __restrict__ h_bf)
{
    int idx = blockIdx.x * 256 + threadIdx.x;   // n*1024 + j
    int n = idx >> 10, j = idx & 1023;
    float ig, fg, gg, og;
    if (GBF) {
        const unsigned short* g = (const unsigned short*)gates + (long long)n * 4096;
        ig = bf2f(g[j]); fg = bf2f(g[1024+j]); gg = bf2f(g[2048+j]); og = bf2f(g[3072+j]);
    } else {
        const float* g = (const float*)gates + (long long)n * 4096;
        ig = g[j]; fg = g[1024+j]; gg = g[2048+j]; og = g[3072+j];
    }
    float cv = FIRST ? 0.0f : c[idx];
    float si = sigmoidf_(ig), sf = sigmoidf_(fg), so = sigmoidf_(og);
    cv = sf * cv + si * tanhf(gg);
    c[idx] = cv;
    float hn = so * tanhf(cv);
    if (j < 512) {
        float hv = qenc[(long long)n * 512 + j] + hn;
        h[(long long)n * 512 + j] = hv;
        h_bf[(long long)n * 512 + j] = f2bf(hv);
    }
}

__global__ __launch_bounds__(256) void dot_kernel(
    const float* __restrict__ h, const float* __restrict__ sg,
    float* __restrict__ out)
{
    int w = threadIdx.x >> 6, lane = threadIdx.x & 63;
    int n = blockIdx.x * 4 + w;
    const float* hp = h + (long long)n * 512 + lane * 8;
    const float* sp = sg + lane * 8;
    float4 a0 = *(const float4*)hp, a1 = *(const float4*)(hp+4);
    float4 b0 = *(const float4*)sp, b1 = *(const float4*)(sp+4);
    float p = a0.x*b0.x + a0.y*b0.y + a0.z*b0.z + a0.w*b0.w
            + a1.x*b1.x + a1.y*b1.y + a1.z*b1.z + a1.w*b1.w;
    #pragma unroll
    for (int off = 32; off > 0; off >>= 1) p += __shfl_down(p, off);
    if (lane == 0) out[n] = p;
}

extern "C" void kernel_launch(void* const* d_in, const int* in_sizes, int n_in,
                              void* d_out, int out_size, void* d_ws, size_t ws_size,
                              hipStream_t stream)
{
    (void)in_sizes; (void)n_in; (void)out_size; (void)ws_size;
    const float* emb       = (const float*)d_in[0];
    const float* gcn_W     = (const float*)d_in[1];
    const float* gcn_wb    = (const float*)d_in[2];
    const float* gcn_b     = (const float*)d_in[3];
    const float* gate_w    = (const float*)d_in[4];
    const float* gate_temp = (const float*)d_in[5];
    const float* p1_b      = (const float*)d_in[7];
    const float* p2_b      = (const float*)d_in[9];
    const float* ln_a      = (const float*)d_in[10];
    const float* ln_b      = (const float*)d_in[11];
    const float* W_hh      = (const float*)d_in[13];
    const float* b_ih      = (const float*)d_in[14];
    const float* b_hh      = (const float*)d_in[15];
    const int*   query     = (const int*)d_in[16];
    const int*   support   = (const int*)d_in[17];
    const int*   q_l1      = (const int*)d_in[18];
    const int*   q_deg_l   = (const int*)d_in[19];
    const int*   q_r1      = (const int*)d_in[20];
    const int*   q_deg_r   = (const int*)d_in[21];
    const int*   s_l1      = (const int*)d_in[22];
    const int*   s_deg_l   = (const int*)d_in[23];
    const int*   s_r1      = (const int*)d_in[24];
    const int*   s_deg_r   = (const int*)d_in[25];
    float* out = (float*)d_out;
    typedef unsigned short us;

    char* w = (char*)d_ws;
    auto take = [&](size_t bytes) { void* p = w; w += (bytes + 255) & ~(size_t)255; return p; };
    us*    q_vec_bf = (us*)   take((size_t)2048*512*2);
    us*    s_vec_bf = (us*)   take((size_t)128*512*2);
    float* q_enc    = (float*)take((size_t)2048*512*4);
    us*    q_enc_bf = (us*)   take((size_t)2048*512*2);
    float* s_enc    = (float*)take((size_t)128*512*4);
    float* s_g      = (float*)take(512*4);
    float* bias0    = (float*)take(4096*4);
    float* svec_g   = (float*)take(4096*4);
    float* c_st     = (float*)take((size_t)2048*1024*4);
    float* h        = (float*)take((size_t)2048*512*4);
    us*    h_bf     = (us*)   take((size_t)2048*512*2);
    us*    wgcn     = (us*)   take((size_t)256*512*2);
    us*    wih      = (us*)   take((size_t)4096*512*2);
    us*    whh      = (us*)   take((size_t)4096*512*2);
    char*  g0region = (char*) take((size_t)2048*4096*2);
    float* gates    = (float*)take((size_t)2048*4096*4);
    // scratch aliases inside g0region (all dead before G0 gemm writes it)
    us*    G0_bf    = (us*)g0region;
    us*    p1w      = (us*)(g0region);
    us*    p2w      = (us*)(g0region + (1<<20));
    us*    h1_q_bf  = (us*)(g0region + (2<<20));
    float* z_q      = (float*)(g0region + (6LL<<20));
    us*    h1_s_bf  = (us*)(g0region + (10LL<<20));
    float* z_s      = (float*)(g0region + (10LL<<20) + (256<<10));

    // 1) weights -> bf16
    preconvert<<<5248, 256, 0, stream>>>(gcn_W, (const float*)d_in[6], (const float*)d_in[8],
        (const float*)d_in[12], W_hh, wgcn, p1w, p2w, wih, whh);

    // 2) neighbor encoders (MFMA)
    ne_fused<<<4106, 256, 0, stream>>>(emb, wgcn, gcn_wb, gcn_b, gate_w, gate_temp,
        q_l1, q_deg_l, q_r1, q_deg_r, s_l1, s_deg_l, s_r1, s_deg_r,
        query, support, q_vec_bf, s_vec_bf);

    // 3) support encoder: p1 (relu, bf16 out), p2 (+x residual), layernorm
    mfma_gemm<1,0,0,0,1,0,1><<<dim3(8,16), 256, 0, stream>>>(q_vec_bf, p1w, p1_b, nullptr, nullptr, nullptr, h1_q_bf, 2048, 1024, 512);
    mfma_gemm<1,0,0,0,1,0,1><<<dim3(8,1),  256, 0, stream>>>(s_vec_bf, p1w, p1_b, nullptr, nullptr, nullptr, h1_s_bf, 5,    1024, 512);
    mfma_gemm<1,0,1,1,0,1,0><<<dim3(4,16), 256, 0, stream>>>(h1_q_bf, p2w, p2_b, nullptr, q_vec_bf, z_q, nullptr, 2048, 512, 1024);
    mfma_gemm<1,0,1,1,0,1,0><<<dim3(4,1),  256, 0, stream>>>(h1_s_bf, p2w, p2_b, nullptr, s_vec_bf, z_s, nullptr, 5,    512, 1024);
    ln_kernel<<<2048, 256, 0, stream>>>(z_q, ln_a, ln_b, q_enc, q_enc_bf);
    ln_kernel<<<5,    256, 0, stream>>>(z_s, ln_a, ln_b, s_enc, nullptr);
    mean5_kernel<<<2, 256, 0, stream>>>(s_enc, s_g);

    // 4) LSTM preludes
    vecadd_kernel<<<16, 256, 0, stream>>>(b_ih, b_hh, bias0, 4096);
    svecg_kernel<<<16, 256, 0, stream>>>(s_g, W_hh, svec_g);
    mfma_gemm<1,0,0,0,0,0,1><<<dim3(32,16), 256, 0, stream>>>(q_enc_bf, wih, bias0, nullptr, nullptr, nullptr, G0_bf, 2048, 4096, 512);

    // 5) LSTM steps (step 1: h_r = 0 -> gates = G0)
    lstm_ew_kernel<true,  true ><<<8192, 256, 0, stream>>>(G0_bf, c_st, q_enc, h, h_bf);
    for (int s2 = 0; s2 < 3; s2++) {
        mfma_gemm<0,1,1,1,0,1,0><<<dim3(32,16), 256, 0, stream>>>(h_bf, whh, nullptr, svec_g, G0_bf, gates, nullptr, 2048, 4096, 512);
        lstm_ew_kernel<false, false><<<8192, 256, 0, stream>>>(gates, c_st, q_enc, h, h_bf);
    }

    // 6) final scores
    dot_kernel<<<512, 256, 0, stream>>>(h, s_g, out);
}

// Round 3
// 883.733 us; speedup vs baseline: 2.4538x; 1.0026x over previous
//
#include <hip/hip_runtime.h>
#include <math.h>

#define PADID 400000

typedef __attribute__((ext_vector_type(8))) short bf16x8;
typedef __attribute__((ext_vector_type(4))) float f32x4;

__device__ __forceinline__ float sigmoidf_(float x){ return 1.0f/(1.0f+__expf(-x)); }
__device__ __forceinline__ float ftanh(float x){ return 1.0f - 2.0f/(__expf(2.0f*x)+1.0f); }

__device__ __forceinline__ unsigned short f2bf(float f){
    unsigned u = __float_as_uint(f);
    u += 0x7FFFu + ((u >> 16) & 1u);
    return (unsigned short)(u >> 16);
}
__device__ __forceinline__ float bf2f(unsigned short s){
    return __uint_as_float(((unsigned)s) << 16);
}

// gate-interleaved permutation: m' -> original gate-major row
__device__ __forceinline__ int perm_orig(int mp){
    int gate = (mp >> 4) & 3;
    int j = (mp >> 6) * 16 + (mp & 15);
    return gate * 1024 + j;
}

// ---------------------------------------------------------------------------
// Weight preconversion fp32 -> bf16 + permutations (one pass).
// ---------------------------------------------------------------------------
__global__ __launch_bounds__(256) void preconvert(
    const float* __restrict__ gcnW, const float* __restrict__ p1W,
    const float* __restrict__ p2W, const float* __restrict__ Wih,
    const float* __restrict__ Whh, const float* __restrict__ b_ih,
    const float* __restrict__ b_hh,
    unsigned short* __restrict__ wgcn, unsigned short* __restrict__ p1w,
    unsigned short* __restrict__ p2w, unsigned short* __restrict__ wih_p,
    unsigned short* __restrict__ whh_p, float* __restrict__ bias0_p)
{
    long long i = ((long long)blockIdx.x * 256 + threadIdx.x) * 4;
    float4 v;
    if (i < 131072LL) {
        v = *(const float4*)(gcnW + i);
        unsigned a0 = f2bf(v.x) | ((unsigned)f2bf(v.y) << 16);
        unsigned a1 = f2bf(v.z) | ((unsigned)f2bf(v.w) << 16);
        *(uint2*)(wgcn + i) = make_uint2(a0, a1);
    } else if (i < 655360LL) {
        long long off = i - 131072LL;
        v = *(const float4*)(p1W + off);
        unsigned a0 = f2bf(v.x) | ((unsigned)f2bf(v.y) << 16);
        unsigned a1 = f2bf(v.z) | ((unsigned)f2bf(v.w) << 16);
        *(uint2*)(p1w + off) = make_uint2(a0, a1);
    } else if (i < 1179648LL) {
        long long off = i - 655360LL;
        v = *(const float4*)(p2W + off);
        unsigned a0 = f2bf(v.x) | ((unsigned)f2bf(v.y) << 16);
        unsigned a1 = f2bf(v.z) | ((unsigned)f2bf(v.w) << 16);
        *(uint2*)(p2w + off) = make_uint2(a0, a1);
    } else if (i < 3276800LL) {
        long long off = i - 1179648LL;
        int mp = (int)(off >> 9), col = (int)(off & 511);
        int orig = perm_orig(mp);
        v = *(const float4*)(Wih + (long long)orig * 512 + col);
        unsigned a0 = f2bf(v.x) | ((unsigned)f2bf(v.y) << 16);
        unsigned a1 = f2bf(v.z) | ((unsigned)f2bf(v.w) << 16);
        *(uint2*)(wih_p + off) = make_uint2(a0, a1);
    } else if (i < 5373952LL) {
        long long off = i - 3276800LL;
        int mp = (int)(off >> 9), col = (int)(off & 511);
        int orig = perm_orig(mp);
        v = *(const float4*)(Whh + (long long)orig * 1024 + col);
        unsigned a0 = f2bf(v.x) | ((unsigned)f2bf(v.y) << 16);
        unsigned a1 = f2bf(v.z) | ((unsigned)f2bf(v.w) << 16);
        *(uint2*)(whh_p + off) = make_uint2(a0, a1);
    } else if (i < 5378048LL) {
        long long off = i - 5373952LL;
        #pragma unroll
        for (int q = 0; q < 4; q++) {
            int mp = (int)off + q;
            int orig = perm_orig(mp);
            bias0_p[mp] = b_ih[orig] + b_hh[orig];
        }
    }
}

// ---------------------------------------------------------------------------
// Neighbor encoder, 2 samples/block. A = gathered emb rows (128 x 512 bf16),
// B = gcn_W bf16 (256 x 512). 4 waves, each 64 rows x 128 cols.
// ---------------------------------------------------------------------------
__device__ __forceinline__ void ne_decode(int s,
    const int* q_l1, const int* q_deg_l, const int* q_r1, const int* q_deg_r,
    const int* s_l1, const int* s_deg_l, const int* s_r1, const int* s_deg_r,
    const int* query, const int* support,
    const int*& conn, const int*& deg, const int*& ids, int& n, int& ids_off, int& row, int& col)
{
    if (s < 2048)      { conn = q_l1; deg = q_deg_l; ids = query;   n = s;      ids_off = 0; row = s;        col = 0;   }
    else if (s < 4096) { conn = q_r1; deg = q_deg_r; ids = query;   n = s-2048; ids_off = 1; row = s-2048;   col = 256; }
    else if (s < 4101) { conn = s_l1; deg = s_deg_l; ids = support; n = s-4096; ids_off = 0; row = 2048+n;   col = 0;   }
    else               { conn = s_r1; deg = s_deg_r; ids = support; n = s-4101; ids_off = 1; row = 2048+n;   col = 256; }
}

__global__ __launch_bounds__(256, 2) void ne_fused(
    const float* __restrict__ emb, const unsigned short* __restrict__ Wbf,
    const float* __restrict__ wb, const float* __restrict__ bb,
    const float* __restrict__ gate_w, const float* __restrict__ gate_temp,
    const int* __restrict__ q_l1, const int* __restrict__ q_deg_l,
    const int* __restrict__ q_r1, const int* __restrict__ q_deg_r,
    const int* __restrict__ s_l1, const int* __restrict__ s_deg_l,
    const int* __restrict__ s_r1, const int* __restrict__ s_deg_r,
    const int* __restrict__ query, const int* __restrict__ support,
    unsigned short* __restrict__ vec_bf)
{
    __shared__ int   rel_s[128];
    __shared__ int   ent_s[128];
    __shared__ unsigned short A_lds[128 * 72];
    __shared__ unsigned short B_lds[256 * 72];
    __shared__ float red[4][4][128];
    __shared__ float gw_s[128];
    __shared__ float gate_sh[2];

    const int bid = blockIdx.x;
    const int t = threadIdx.x;
    const int lane = t & 63, w = t >> 6, lr = lane & 15, kg = lane >> 4;
    const int si_w = w >> 1;            // which sample this wave computes
    const int wc0 = (w & 1) * 128;      // col base of this wave

    // load conn for both samples
    {
        int si = t >> 7, u = t & 127;
        const int *conn, *deg, *ids; int n, ids_off, row, col;
        ne_decode(bid*2 + si, q_l1,q_deg_l,q_r1,q_deg_r,s_l1,s_deg_l,s_r1,s_deg_r,
                  query, support, conn, deg, ids, n, ids_off, row, col);
        int v = conn[n*128 + u];
        if (u & 1) ent_s[si*64 + (u>>1)] = v; else rel_s[si*64 + (u>>1)] = v;
    }
    __syncthreads();
    if (t < 128) {
        int r = rel_s[t];
        gw_s[t] = gate_w[(r == PADID) ? 0 : r];
    }
    __syncthreads();
    if ((t & 63) == 0 && t < 128) {
        int si = t >> 6;
        const int *conn, *deg, *ids; int n, ids_off, row, col;
        ne_decode(bid*2 + si, q_l1,q_deg_l,q_r1,q_deg_r,s_l1,s_deg_l,s_r1,s_deg_r,
                  query, support, conn, deg, ids, n, ids_off, row, col);
        float s = 0.0f;
        for (int k = 0; k < 64; k++) s += gw_s[si*64 + k];
        float g = sigmoidf_((s * (1.0f/64.0f)) / gate_temp[0]);
        if (!((float)deg[n] > 0.0f)) g = 1.0f;
        gate_sh[si] = g;
    }

    f32x4 acc[4][8];
    #pragma unroll
    for (int i = 0; i < 4; i++)
        #pragma unroll
        for (int j = 0; j < 8; j++)
            acc[i][j] = (f32x4){0.f,0.f,0.f,0.f};

    const int rr = t >> 1, half = t & 1;  // A-stage: row 0..127, col half
    for (int ch = 0; ch < 8; ch++) {
        const int side = (ch >= 4);
        const int cg0 = (ch & 3) * 64;
        // A stage: 128 rows x 64 cols fp32 gather -> bf16
        {
            int rowid = side ? ent_s[rr] : rel_s[rr];
            const float* src = emb + (long long)rowid * 256 + cg0 + half * 32;
            unsigned short* dst = &A_lds[rr*72 + half*32];
            #pragma unroll
            for (int q = 0; q < 4; q++) {
                float4 v0 = *(const float4*)(src + q*8);
                float4 v1 = *(const float4*)(src + q*8 + 4);
                bf16x8 o;
                o[0]=(short)f2bf(v0.x); o[1]=(short)f2bf(v0.y); o[2]=(short)f2bf(v0.z); o[3]=(short)f2bf(v0.w);
                o[4]=(short)f2bf(v1.x); o[5]=(short)f2bf(v1.y); o[6]=(short)f2bf(v1.z); o[7]=(short)f2bf(v1.w);
                *(bf16x8*)(dst + q*8) = o;
            }
        }
        // B stage: 256 rows x 64 cols bf16 copy
        #pragma unroll
        for (int j = 0; j < 8; j++) {
            int row = j * 32 + (t >> 3);
            bf16x8 v = *(const bf16x8*)(Wbf + (long long)row * 512 + ch*64 + (t & 7) * 8);
            *(bf16x8*)&B_lds[row*72 + (t & 7) * 8] = v;
        }
        __syncthreads();
        #pragma unroll
        for (int ks = 0; ks < 64; ks += 32) {
            bf16x8 a[4], b[8];
            #pragma unroll
            for (int rt = 0; rt < 4; rt++)
                a[rt] = *(const bf16x8*)&A_lds[(si_w*64 + rt*16 + lr)*72 + ks + kg*8];
            #pragma unroll
            for (int ct = 0; ct < 8; ct++)
                b[ct] = *(const bf16x8*)&B_lds[(wc0 + ct*16 + lr)*72 + ks + kg*8];
            #pragma unroll
            for (int rt = 0; rt < 4; rt++)
                #pragma unroll
                for (int ct = 0; ct < 8; ct++)
                    acc[rt][ct] = __builtin_amdgcn_mfma_f32_16x16x32_bf16(a[rt], b[ct], acc[rt][ct], 0, 0, 0);
        }
        __syncthreads();
    }

    // epilogue: bias + leaky_relu + PAD mask + per-sample row sum
    #pragma unroll
    for (int ct = 0; ct < 8; ct++) {
        int d = wc0 + ct*16 + lr;
        float bd = wb[d] + bb[d];
        float pp = 0.0f;
        #pragma unroll
        for (int rt = 0; rt < 4; rt++) {
            int rbase = si_w*64 + rt*16 + kg*4;
            #pragma unroll
            for (int reg = 0; reg < 4; reg++) {
                if (rel_s[rbase + reg] != PADID) {
                    float v = acc[rt][ct][reg] + bd;
                    v = (v > 0.0f) ? v : 0.01f * v;
                    pp += v;
                }
            }
        }
        red[w][kg][ct*16 + lr] = pp;
    }
    __syncthreads();

    // final: thread t -> col t for both samples
    #pragma unroll
    for (int si = 0; si < 2; si++) {
        int wv = si*2 + (t >> 7), cl = t & 127;
        float agg = red[wv][0][cl] + red[wv][1][cl] + red[wv][2][cl] + red[wv][3][cl];
        const int *conn, *deg, *ids; int n, ids_off, row, col;
        ne_decode(bid*2 + si, q_l1,q_deg_l,q_r1,q_deg_r,s_l1,s_deg_l,s_r1,s_deg_r,
                  query, support, conn, deg, ids, n, ids_off, row, col);
        float degf = fmaxf((float)deg[n], 1.0f);
        agg /= degf;
        int id = ids[n*2 + ids_off];
        float o = ftanh(emb[(long long)id * 256 + t] + gate_sh[si] * agg);
        vec_bf[(long long)row * 512 + col + t] = f2bf(o);
    }
}

// ---------------------------------------------------------------------------
// Generic bf16 MFMA GEMM (support encoder): C = act(A.B^T + bias + add)
// 128x128 tile, BK=64, LDS stride 72.
// ---------------------------------------------------------------------------
template<int HB, int HADD, int RELU, int WF, int WB>
__global__ __launch_bounds__(256) void mfma_gemm(
    const unsigned short* __restrict__ A, const unsigned short* __restrict__ B,
    const float* __restrict__ bias, const unsigned short* __restrict__ addbf,
    float* __restrict__ Cf, unsigned short* __restrict__ Cb, int N, int M, int K)
{
    __shared__ unsigned short A_lds[128 * 72];
    __shared__ unsigned short B_lds[128 * 72];
    const int t = threadIdx.x;
    const int bm0 = blockIdx.x * 128, bn0 = blockIdx.y * 128;
    const int lane = t & 63, w = t >> 6, wn = w >> 1, wm = w & 1;
    const int lr = lane & 15, kg = lane >> 4;

    f32x4 acc[4][4];
    #pragma unroll
    for (int i = 0; i < 4; i++)
        #pragma unroll
        for (int j = 0; j < 4; j++)
            acc[i][j] = (f32x4){0.f,0.f,0.f,0.f};

    const int r = t >> 1, half = t & 1;
    const unsigned short* Ap = A + (size_t)(bn0 + r) * K + half * 32;
    const unsigned short* Bp = B + (size_t)(bm0 + r) * K + half * 32;
    unsigned short* Aw = &A_lds[r*72 + half*32];
    unsigned short* Bw = &B_lds[r*72 + half*32];

    for (int c0 = 0; c0 < K; c0 += 64) {
        #pragma unroll
        for (int q = 0; q < 4; q++) {
            *(bf16x8*)(Aw + q*8) = *(const bf16x8*)(Ap + c0 + q*8);
            *(bf16x8*)(Bw + q*8) = *(const bf16x8*)(Bp + c0 + q*8);
        }
        __syncthreads();
        #pragma unroll
        for (int ks = 0; ks < 64; ks += 32) {
            bf16x8 a[4], b[4];
            #pragma unroll
            for (int rt = 0; rt < 4; rt++)
                a[rt] = *(const bf16x8*)&A_lds[(wn*64 + rt*16 + lr)*72 + ks + kg*8];
            #pragma unroll
            for (int ct = 0; ct < 4; ct++)
                b[ct] = *(const bf16x8*)&B_lds[(wm*64 + ct*16 + lr)*72 + ks + kg*8];
            #pragma unroll
            for (int rt = 0; rt < 4; rt++)
                #pragma unroll
                for (int ct = 0; ct < 4; ct++)
                    acc[rt][ct] = __builtin_amdgcn_mfma_f32_16x16x32_bf16(a[rt], b[ct], acc[rt][ct], 0, 0, 0);
        }
        __syncthreads();
    }

    float bsum[4];
    #pragma unroll
    for (int ct = 0; ct < 4; ct++)
        bsum[ct] = HB ? bias[bm0 + wm*64 + ct*16 + lr] : 0.0f;
    #pragma unroll
    for (int rt = 0; rt < 4; rt++) {
        #pragma unroll
        for (int reg = 0; reg < 4; reg++) {
            int n = bn0 + wn*64 + rt*16 + kg*4 + reg;
            if (n < N) {
                size_t rowb = (size_t)n * M + bm0 + wm*64;
                #pragma unroll
                for (int ct = 0; ct < 4; ct++) {
                    size_t idx = rowb + ct*16 + lr;
                    float v = acc[rt][ct][reg] + bsum[ct];
                    if (HADD) v += bf2f(addbf[idx]);
                    if (RELU) v = fmaxf(v, 0.0f);
                    if (WF) Cf[idx] = v;
                    if (WB) Cb[idx] = f2bf(v);
                }
            }
        }
    }
}

// ---------------------------------------------------------------------------
// LSTM GEMM with fused elementwise. Gate-interleaved layout (perm m').
// FIRST: gates = A.B^T + bias0_p; writes G0_bf, c=si*tanh(g), h.
// else:  gates = A.B^T + svec_p + bf(G0); c = sf*c + si*tanh(g); h.
// N=2048, M=4096, K=512, grid (32,16).
// ---------------------------------------------------------------------------
template<int FIRST>
__global__ __launch_bounds__(256, 2) void lstm_gemm(
    const unsigned short* __restrict__ A, const unsigned short* __restrict__ B,
    const float* __restrict__ biasv, unsigned short* __restrict__ G0,
    float* __restrict__ c_st, const float* __restrict__ qenc,
    unsigned short* __restrict__ h_bf)
{
    __shared__ unsigned short A_lds[128 * 72];
    __shared__ unsigned short B_lds[128 * 72];
    const int t = threadIdx.x;
    const int bm0 = blockIdx.x * 128, bn0 = blockIdx.y * 128;
    const int lane = t & 63, w = t >> 6, wn = w >> 1, wm = w & 1;
    const int lr = lane & 15, kg = lane >> 4;

    f32x4 acc[4][4];
    #pragma unroll
    for (int i = 0; i < 4; i++)
        #pragma unroll
        for (int j = 0; j < 4; j++)
            acc[i][j] = (f32x4){0.f,0.f,0.f,0.f};

    const int r = t >> 1, half = t & 1;
    const unsigned short* Ap = A + (size_t)(bn0 + r) * 512 + half * 32;
    const unsigned short* Bp = B + (size_t)(bm0 + r) * 512 + half * 32;
    unsigned short* Aw = &A_lds[r*72 + half*32];
    unsigned short* Bw = &B_lds[r*72 + half*32];

    for (int c0 = 0; c0 < 512; c0 += 64) {
        #pragma unroll
        for (int q = 0; q < 4; q++) {
            *(bf16x8*)(Aw + q*8) = *(const bf16x8*)(Ap + c0 + q*8);
            *(bf16x8*)(Bw + q*8) = *(const bf16x8*)(Bp + c0 + q*8);
        }
        __syncthreads();
        #pragma unroll
        for (int ks = 0; ks < 64; ks += 32) {
            bf16x8 a[4], b[4];
            #pragma unroll
            for (int rt = 0; rt < 4; rt++)
                a[rt] = *(const bf16x8*)&A_lds[(wn*64 + rt*16 + lr)*72 + ks + kg*8];
            #pragma unroll
            for (int ct = 0; ct < 4; ct++)
                b[ct] = *(const bf16x8*)&B_lds[(wm*64 + ct*16 + lr)*72 + ks + kg*8];
            #pragma unroll
            for (int rt = 0; rt < 4; rt++)
                #pragma unroll
                for (int ct = 0; ct < 4; ct++)
                    acc[rt][ct] = __builtin_amdgcn_mfma_f32_16x16x32_bf16(a[rt], b[ct], acc[rt][ct], 0, 0, 0);
        }
        __syncthreads();
    }

    const int g0col = (bm0 + wm*64) >> 6;     // 0..63
    const int j = g0col*16 + lr;              // 0..1023
    float e[4];
    #pragma unroll
    for (int ct = 0; ct < 4; ct++)
        e[ct] = biasv[bm0 + wm*64 + ct*16 + lr];

    #pragma unroll
    for (int rt = 0; rt < 4; rt++) {
        #pragma unroll
        for (int reg = 0; reg < 4; reg++) {
            int n = bn0 + wn*64 + rt*16 + kg*4 + reg;
            size_t gbase = (size_t)n * 4096 + bm0 + wm*64;
            float gi = acc[rt][0][reg] + e[0];
            float gf = acc[rt][1][reg] + e[1];
            float gg = acc[rt][2][reg] + e[2];
            float go = acc[rt][3][reg] + e[3];
            if (FIRST) {
                G0[gbase + 0*16 + lr] = f2bf(gi);
                G0[gbase + 1*16 + lr] = f2bf(gf);
                G0[gbase + 2*16 + lr] = f2bf(gg);
                G0[gbase + 3*16 + lr] = f2bf(go);
            } else {
                gi += bf2f(G0[gbase + 0*16 + lr]);
                gf += bf2f(G0[gbase + 1*16 + lr]);
                gg += bf2f(G0[gbase + 2*16 + lr]);
                go += bf2f(G0[gbase + 3*16 + lr]);
            }
            size_t cidx = (size_t)n * 1024 + j;
            float cprev = FIRST ? 0.0f : c_st[cidx];
            float cv = sigmoidf_(gf) * cprev + sigmoidf_(gi) * ftanh(gg);
            c_st[cidx] = cv;
            float hn = sigmoidf_(go) * ftanh(cv);
            if (j < 512)
                h_bf[(size_t)n * 512 + j] = f2bf(qenc[(size_t)n * 512 + j] + hn);
        }
    }
}

// ---------------------------------------------------------------------------
// LayerNorm ddof=1, row length 512; fp32 + bf16 outputs
// ---------------------------------------------------------------------------
__global__ __launch_bounds__(256) void ln_kernel(
    const float* __restrict__ z, const float* __restrict__ a,
    const float* __restrict__ b, float* __restrict__ o,
    unsigned short* __restrict__ ob)
{
    __shared__ float red[256];
    int n = blockIdx.x, t = threadIdx.x;
    const float* zp = z + (long long)n * 512;
    float2 v = *(const float2*)(zp + t*2);
    red[t] = v.x + v.y;
    __syncthreads();
    for (int off = 128; off > 0; off >>= 1) {
        if (t < off) red[t] += red[t+off];
        __syncthreads();
    }
    float mu = red[0] * (1.0f/512.0f);
    __syncthreads();
    float d0 = v.x - mu, d1 = v.y - mu;
    red[t] = d0*d0 + d1*d1;
    __syncthreads();
    for (int off = 128; off > 0; off >>= 1) {
        if (t < off) red[t] += red[t+off];
        __syncthreads();
    }
    float var = red[0] * (1.0f/511.0f);
    float inv = 1.0f / (sqrtf(var) + 1e-3f);
    float r0 = d0 * inv * a[t*2]   + b[t*2];
    float r1 = d1 * inv * a[t*2+1] + b[t*2+1];
    float* op = o + (long long)n * 512;
    op[t*2] = r0; op[t*2+1] = r1;
    unsigned short* obp = ob + (long long)n * 512;
    obp[t*2] = f2bf(r0); obp[t*2+1] = f2bf(r1);
}

__global__ __launch_bounds__(256) void mean5_kernel(
    const float* __restrict__ se, float* __restrict__ sg)
{
    int d = blockIdx.x * 256 + threadIdx.x;
    if (d < 512) {
        float s = 0.0f;
        #pragma unroll
        for (int f = 0; f < 5; f++) s += se[f*512 + d];
        sg[d] = s * 0.2f;
    }
}

// svec_p[m'] = sum_k s_g[k] * W_hh[orig(m')][512+k]
__global__ __launch_bounds__(256) void svecg_kernel(
    const float* __restrict__ sg, const float* __restrict__ Whh,
    float* __restrict__ outv)
{
    __shared__ float sgl[512];
    int t = threadIdx.x;
    sgl[t] = sg[t]; sgl[256+t] = sg[256+t];
    __syncthreads();
    int mp = blockIdx.x * 256 + t;
    int orig = perm_orig(mp);
    const float* wp = Whh + (long long)orig * 1024 + 512;
    float s = 0.0f;
    for (int k = 0; k < 512; k += 4) {
        float4 wv = *(const float4*)(wp + k);
        s += sgl[k]*wv.x + sgl[k+1]*wv.y + sgl[k+2]*wv.z + sgl[k+3]*wv.w;
    }
    outv[mp] = s;
}

// out[n] = dot(h_bf[n], s_g)
__global__ __launch_bounds__(256) void dot_kernel(
    const unsigned short* __restrict__ h_bf, const float* __restrict__ sg,
    float* __restrict__ out)
{
    int w = threadIdx.x >> 6, lane = threadIdx.x & 63;
    int n = blockIdx.x * 4 + w;
    bf16x8 hv = *(const bf16x8*)(h_bf + (long long)n * 512 + lane * 8);
    const float* sp = sg + lane * 8;
    float4 b0 = *(const float4*)sp, b1 = *(const float4*)(sp+4);
    float bs[8] = {b0.x,b0.y,b0.z,b0.w,b1.x,b1.y,b1.z,b1.w};
    float p = 0.0f;
    #pragma unroll
    for (int q = 0; q < 8; q++) p += bf2f((unsigned short)hv[q]) * bs[q];
    #pragma unroll
    for (int off = 32; off > 0; off >>= 1) p += __shfl_down(p, off);
    if (lane == 0) out[n] = p;
}

extern "C" void kernel_launch(void* const* d_in, const int* in_sizes, int n_in,
                              void* d_out, int out_size, void* d_ws, size_t ws_size,
                              hipStream_t stream)
{
    (void)in_sizes; (void)n_in; (void)out_size; (void)ws_size;
    const float* emb       = (const float*)d_in[0];
    const float* gcn_W     = (const float*)d_in[1];
    const float* gcn_wb    = (const float*)d_in[2];
    const float* gcn_b     = (const float*)d_in[3];
    const float* gate_w    = (const float*)d_in[4];
    const float* gate_temp = (const float*)d_in[5];
    const float* p1_W      = (const float*)d_in[6];
    const float* p1_b      = (const float*)d_in[7];
    const float* p2_W      = (const float*)d_in[8];
    const float* p2_b      = (const float*)d_in[9];
    const float* ln_a      = (const float*)d_in[10];
    const float* ln_b      = (const float*)d_in[11];
    const float* W_ih      = (const float*)d_in[12];
    const float* W_hh      = (const float*)d_in[13];
    const float* b_ih      = (const float*)d_in[14];
    const float* b_hh      = (const float*)d_in[15];
    const int*   query     = (const int*)d_in[16];
    const int*   support   = (const int*)d_in[17];
    const int*   q_l1      = (const int*)d_in[18];
    const int*   q_deg_l   = (const int*)d_in[19];
    const int*   q_r1      = (const int*)d_in[20];
    const int*   q_deg_r   = (const int*)d_in[21];
    const int*   s_l1      = (const int*)d_in[22];
    const int*   s_deg_l   = (const int*)d_in[23];
    const int*   s_r1      = (const int*)d_in[24];
    const int*   s_deg_r   = (const int*)d_in[25];
    float* out = (float*)d_out;
    typedef unsigned short us;

    char* wp_ = (char*)d_ws;
    auto take = [&](size_t bytes) { void* p = wp_; wp_ += (bytes + 255) & ~(size_t)255; return p; };
    us*    vec_bf  = (us*)   take((size_t)2176*512*2);   // rows 0..2047 q, 2048..2052 s
    us*    h1_bf   = (us*)   take((size_t)2176*1024*2);
    float* z_buf   = (float*)take((size_t)2176*512*4);
    float* enc_f   = (float*)take((size_t)2176*512*4);
    us*    enc_bf  = (us*)   take((size_t)2176*512*2);
    float* s_g     = (float*)take(512*4);
    float* bias0_p = (float*)take(4096*4);
    float* svec_p  = (float*)take(4096*4);
    float* c_st    = (float*)take((size_t)2048*1024*4);
    us*    h_bf    = (us*)   take((size_t)2048*512*2);
    us*    wgcn    = (us*)   take((size_t)256*512*2);
    us*    p1w     = (us*)   take((size_t)1024*512*2);
    us*    p2w     = (us*)   take((size_t)512*1024*2);
    us*    wih_p   = (us*)   take((size_t)4096*512*2);
    us*    whh_p   = (us*)   take((size_t)4096*512*2);
    us*    G0_bf   = (us*)   take((size_t)2048*4096*2);

    // 1) weights -> bf16 (+ gate-interleave permutation for LSTM)
    preconvert<<<5252, 256, 0, stream>>>(gcn_W, p1_W, p2_W, W_ih, W_hh, b_ih, b_hh,
        wgcn, p1w, p2w, wih_p, whh_p, bias0_p);

    // 2) neighbor encoders (2 samples/block)
    ne_fused<<<2053, 256, 0, stream>>>(emb, wgcn, gcn_wb, gcn_b, gate_w, gate_temp,
        q_l1, q_deg_l, q_r1, q_deg_r, s_l1, s_deg_l, s_r1, s_deg_r,
        query, support, vec_bf);

    // 3) support encoder over q+s rows (N=2053): p1 relu -> p2 +resid -> LN
    mfma_gemm<1,0,1,0,1><<<dim3(8,17), 256, 0, stream>>>(vec_bf, p1w, p1_b, nullptr, nullptr, h1_bf, 2053, 1024, 512);
    mfma_gemm<1,1,0,1,0><<<dim3(4,17), 256, 0, stream>>>(h1_bf, p2w, p2_b, vec_bf, z_buf, nullptr, 2053, 512, 1024);
    ln_kernel<<<2053, 256, 0, stream>>>(z_buf, ln_a, ln_b, enc_f, enc_bf);
    mean5_kernel<<<2, 256, 0, stream>>>(enc_f + (size_t)2048*512, s_g);
    svecg_kernel<<<16, 256, 0, stream>>>(s_g, W_hh, svec_p);

    // 4) LSTM: G0 gemm + step-1 ew fused, then 3 fused steps
    lstm_gemm<1><<<dim3(32,16), 256, 0, stream>>>(enc_bf, wih_p, bias0_p, G0_bf, c_st, enc_f, h_bf);
    for (int s2 = 0; s2 < 3; s2++)
        lstm_gemm<0><<<dim3(32,16), 256, 0, stream>>>(h_bf, whh_p, svec_p, G0_bf, c_st, enc_f, h_bf);

    // 5) final scores
    dot_kernel<<<512, 256, 0, stream>>>(h_bf, s_g, out);
}